// Round 9
// baseline (1884.369 us; speedup 1.0000x reference)
//
#include <hip/hip_runtime.h>
#include <hip/hip_bf16.h>
#include <math.h>
#include <stdint.h>

typedef __attribute__((ext_vector_type(8))) short short8;
typedef __attribute__((ext_vector_type(4))) float f32x4;
typedef __attribute__((ext_vector_type(4))) unsigned int uint4v;

#define T_ 512

__device__ __forceinline__ unsigned short bf16rn(float f) {
  union { float f; unsigned u; } x; x.f = f;
  unsigned r = x.u + 0x7FFF + ((x.u >> 16) & 1);
  return (unsigned short)(r >> 16);
}

__device__ __forceinline__ void gload16(const void* gsrc, void* ldst) {
  __builtin_amdgcn_global_load_lds(
      (const __attribute__((address_space(1))) unsigned int*)gsrc,
      (__attribute__((address_space(3))) unsigned int*)ldst, 16, 0, 0);
}

// raw barrier: LDS-visibility only (lgkmcnt), NO vmcnt drain.  The "memory"
// clobber is the compiler fence (prevents LDS-value caching across it).
__device__ __forceinline__ void wg_barrier() {
  __builtin_amdgcn_sched_barrier(0);
  asm volatile("s_waitcnt lgkmcnt(0)" ::: "memory");
  __builtin_amdgcn_sched_barrier(0);
  __builtin_amdgcn_s_barrier();
  __builtin_amdgcn_sched_barrier(0);
}

// ---------------- conv1 + pool (fp32 math, bf16 out), 8 frames/block ----------------
__global__ __launch_bounds__(256) void conv1_kernel(
    const float* __restrict__ phone, const float* __restrict__ w1,
    const float* __restrict__ b1, ushort* __restrict__ out1b) {
  __shared__ float ws[128 * 77];
  __shared__ float bs[128];
  __shared__ float xs[8][7][52];
  const int tid = threadIdx.x;
  const int n0 = blockIdx.x * 8;
  for (int idx = tid; idx < 9856; idx += 256) ws[idx] = w1[idx];
  if (tid < 128) bs[tid] = b1[tid];
  for (int idx = tid; idx < 2800; idx += 256) {
    int fi = idx / 350, r = idx - fi * 350;
    int ll = r / 7, c = r - ll * 7;
    xs[fi][c][ll] = phone[(size_t)(n0 + fi) * 350 + r];
  }
  __syncthreads();

  const int o = tid >> 1, ph = tid & 1;
  const float* wo = ws + o * 77;
  const float bb = bs[o];
  for (int fi = 0; fi < 8; ++fi) {
    float acc0[10], acc1[10];
#pragma unroll
    for (int q = 0; q < 10; ++q) { acc0[q] = 0.f; acc1[q] = 0.f; }
    for (int i = 0; i < 7; ++i) {
      float wr[11];
#pragma unroll
      for (int k = 0; k < 11; ++k) wr[k] = wo[i * 11 + k];
#pragma unroll
      for (int q = 0; q < 10; ++q) {
        int p = ph * 10 + q;
        int base = 2 * p;
        float xv[12];
#pragma unroll
        for (int j = 0; j < 12; ++j) xv[j] = xs[fi][i][base + j];
        float s0 = 0.f, s1 = 0.f;
#pragma unroll
        for (int k = 0; k < 11; ++k) {
          s0 += xv[k] * wr[k];
          s1 += xv[k + 1] * wr[k];
        }
        acc0[q] += s0;
        acc1[q] += s1;
      }
    }
#pragma unroll
    for (int q = 0; q < 10; ++q) {
      int p = ph * 10 + q;
      out1b[((size_t)(n0 + fi) * 128 + o) * 20 + p] =
          bf16rn(fmaxf(acc0[q], acc1[q]) + bb);
    }
  }
}

// ---------------- fp32 -> bf16 convert ----------------
__global__ __launch_bounds__(256) void f32_to_bf16(
    const float* __restrict__ src, ushort* __restrict__ dst, int n4) {
  int i = blockIdx.x * 256 + threadIdx.x;
  if (i < n4) {
    float4 v = ((const float4*)src)[i];
    ushort4 o;
    o.x = bf16rn(v.x); o.y = bf16rn(v.y); o.z = bf16rn(v.z); o.w = bf16rn(v.w);
    ((ushort4*)dst)[i] = o;
  }
}

// ---------------- stage h0 -> tagged bf16 fragments (parity-0 buffer, tag 0) ----------------
__global__ __launch_bounds__(256) void stage_h0(
    const float* __restrict__ h0, unsigned long long* __restrict__ hxt) {
  const int tid = threadIdx.x;
  const int b = tid >> 4, x = tid & 15;
#pragma unroll
  for (int q = 0; q < 16; ++q) {
    int d = (x + q * 16) * 2;
    int s = d >> 5, fqq = (d >> 3) & 3, k = (d & 7) >> 1;
    int lane = b | (fqq << 4);
    float2 h2 = *(const float2*)(h0 + (size_t)b * 512 + d);
    unsigned pk = (unsigned)bf16rn(h2.x) | ((unsigned)bf16rn(h2.y) << 16);
    hxt[((size_t)s * 64 + lane) * 4 + k] = (unsigned long long)pk;  // tag = 0
  }
}

// ---------------- bf16 MFMA GEMM: C = A @ W^T + bias ----------------
template <int AM, int EM>
__global__ __launch_bounds__(256) void gemm_bf16(
    const ushort* __restrict__ A, const ushort* __restrict__ W,
    const float* __restrict__ bias, void* __restrict__ Cout,
    int K, int lda, int ldc) {
  __shared__ ushort As[128 * 64];
  __shared__ ushort Bs[128 * 64];
  __shared__ ushort tbl[1152];
  const int tid = threadIdx.x;
  const int l = tid & 63, wv = tid >> 6;
  const int wr = wv >> 1, wc = wv & 1;
  const int fr = l & 15, fq = l >> 4;
  const int bm0 = blockIdx.x * 128, bn0 = blockIdx.y * 128;

  if (AM == 1) {
    for (int idx = tid; idx < 1152; idx += 256) {
      int i2 = idx / 9, kp = idx - i2 * 9;
      tbl[idx] = (ushort)(i2 * 20 + kp);
    }
    __syncthreads();
  }

  f32x4 acc[4][4];
#pragma unroll
  for (int mi = 0; mi < 4; ++mi)
#pragma unroll
    for (int ni = 0; ni < 4; ++ni) acc[mi][ni] = (f32x4)0.f;

  const int pr8 = l >> 3;
  const int pc = l & 7;
  const int nkt = K >> 6;
  for (int kt = 0; kt < nkt; ++kt) {
    const int k0 = kt << 6;
#pragma unroll
    for (int i = 0; i < 4; ++i) {
      int q = wv * 4 + i;
      int prow = q * 8 + pr8;
      int lc = pc ^ (prow & 7);
      gload16(W + (size_t)(bn0 + prow) * K + k0 + lc * 8, &Bs[q * 512]);
    }
    if (AM == 0) {
#pragma unroll
      for (int i = 0; i < 4; ++i) {
        int q = wv * 4 + i;
        int prow = q * 8 + pr8;
        int lc = pc ^ (prow & 7);
        gload16(A + (size_t)(bm0 + prow) * lda + k0 + lc * 8, &As[q * 512]);
      }
    } else {
      // im2col gather via LDS index table
#pragma unroll
      for (int q = 0; q < 16; ++q) {
        int idx = tid + q * 256;        // 4096 pair items
        int row = idx >> 5, c0 = (idx & 31) * 2;
        int m = bm0 + row;
        int n = m / 12, pos = m - n * 12;
        int kk = k0 + c0;
        const ushort* an = A + (size_t)n * 2560 + pos;
        uint e0 = an[tbl[kk]];
        uint e1 = an[tbl[kk + 1]];
        *(uint*)&As[row * 64 + (((c0 >> 3) ^ (row & 7)) << 3) + (c0 & 7)] =
            e0 | (e1 << 16);
      }
    }
    __syncthreads();
#pragma unroll
    for (int ks = 0; ks < 2; ++ks) {
      short8 af[4], bfr[4];
#pragma unroll
      for (int mi = 0; mi < 4; ++mi) {
        int row = wr * 64 + mi * 16 + fr;
        af[mi] = *(const short8*)&As[row * 64 + (((ks * 4 + fq) ^ (row & 7)) << 3)];
      }
#pragma unroll
      for (int ni = 0; ni < 4; ++ni) {
        int row = wc * 64 + ni * 16 + fr;
        bfr[ni] = *(const short8*)&Bs[row * 64 + (((ks * 4 + fq) ^ (row & 7)) << 3)];
      }
#pragma unroll
      for (int mi = 0; mi < 4; ++mi)
#pragma unroll
        for (int ni = 0; ni < 4; ++ni)
          acc[mi][ni] = __builtin_amdgcn_mfma_f32_16x16x32_bf16(
              af[mi], bfr[ni], acc[mi][ni], 0, 0, 0);
    }
    __syncthreads();
  }

#pragma unroll
  for (int ni = 0; ni < 4; ++ni) {
    int col = bn0 + wc * 64 + ni * 16 + fr;
    float bv = bias[col];
#pragma unroll
    for (int mi = 0; mi < 4; ++mi) {
      int mbase = bm0 + wr * 64 + mi * 16 + fq * 4;
      if (EM == 0) {
        ushort* C = (ushort*)Cout;
#pragma unroll
        for (int j = 0; j < 4; ++j)
          C[(size_t)(mbase + j) * ldc + col] = bf16rn(acc[mi][ni][j] + bv);
      } else if (EM == 1) {
        ushort* C = (ushort*)Cout;
#pragma unroll
        for (int j = 0; j < 4; j += 2) {
          int m = mbase + j;
          int n = m / 12, pos = m - n * 12;
          float v = fmaxf(acc[mi][ni][j], acc[mi][ni][j + 1]) + bv;
          C[(size_t)n * 1536 + col * 6 + (pos >> 1)] = bf16rn(v);
        }
      } else {
        float* C = (float*)Cout;
#pragma unroll
        for (int j = 0; j < 4; ++j) {
          int m = mbase + j;
          int b = m >> 9, tt = m & 511;
          C[((size_t)tt * 16 + b) * 1536 + col] = acc[mi][ni][j] + bv;
        }
      }
    }
  }
}

// ---------------- persistent GRU: tagged exchange, raw barriers, progressive poll ----------------
// 16 WGs x 384 thr.  Waves 0-3 = gate/producer (also MFMA); waves 4-5 =
// pollers (also MFMA).  Key changes vs r8: (1) in-loop barriers are raw
// s_barrier + lgkmcnt-only (no vmcnt drain -> gi prefetch / hsbuf / hxt
// stores genuinely off the critical path; they self-drain at next step's
// gi first-use);  (2) progressive per-line poll (matched lines deposit and
// drop out);  (3) own fragment (line m == w) written to LDS directly by
// gate threads, skipped by pollers.
__global__ __launch_bounds__(384) void gru_persistent(
    const float* __restrict__ h0, const float* __restrict__ gi,
    const float* __restrict__ whh, const float* __restrict__ bhh,
    float* __restrict__ hsbuf, unsigned long long* __restrict__ hxt) {
  __shared__ float gh_lds[6 * 256];
  __shared__ unsigned afl[16 * 64 * 4];  // 16KB: [s][lane][4] pk words
  const int tid = threadIdx.x;
  const int w = blockIdx.x;              // 0..15
  const int l = tid & 63, v = tid >> 6;  // wave 0..5
  const int fr = l & 15, fq = l >> 4;
  const int g = v >> 1, half = v & 1;
  const int o = g * 512 + w * 32 + half * 16 + fr;

  // persistent Whh B-fragments (64 VGPR, all waves)
  short8 bfrag[16];
#pragma unroll
  for (int s = 0; s < 16; ++s) {
    const float* wp = whh + (size_t)o * 512 + s * 32 + fq * 8;
    float4 w0 = *(const float4*)wp;
    float4 w1 = *(const float4*)(wp + 4);
    short8 bb;
    bb[0] = (short)bf16rn(w0.x); bb[1] = (short)bf16rn(w0.y);
    bb[2] = (short)bf16rn(w0.z); bb[3] = (short)bf16rn(w0.w);
    bb[4] = (short)bf16rn(w1.x); bb[5] = (short)bf16rn(w1.y);
    bb[6] = (short)bf16rn(w1.z); bb[7] = (short)bf16rn(w1.w);
    bfrag[s] = bb;
  }
  const float bo = bhh[o];

  // gate-thread persistent state (threads 0..255): pair (jl, jl+1)
  const int b = tid >> 4, jp = tid & 15, jl = jp * 2;
  const bool gthr = (tid < 256);
  const int pt = tid - 256;              // poller index 0..127 (waves 4,5)
  float hA = 0.f, hB = 0.f;
  float giC0 = 0.f, giC1 = 0.f, giC2 = 0.f, giC3 = 0.f, giC4 = 0.f, giC5 = 0.f;
  float giN0 = 0.f, giN1 = 0.f, giN2 = 0.f, giN3 = 0.f, giN4 = 0.f, giN5 = 0.f;
  if (gthr) {
    float2 h2 = *(const float2*)(h0 + (size_t)b * 512 + w * 32 + jl);
    hA = h2.x; hB = h2.y;
    const float* g0 = gi + (size_t)b * 1536 + w * 32 + jl;           // gi[0]
    float2 r0 = *(const float2*)(g0);
    float2 r1 = *(const float2*)(g0 + 512);
    float2 r2 = *(const float2*)(g0 + 1024);
    giC0 = r0.x; giC3 = r0.y; giC1 = r1.x; giC4 = r1.y; giC2 = r2.x; giC5 = r2.y;
    const float* g1 = gi + (size_t)(16 + b) * 1536 + w * 32 + jl;    // gi[1]
    float2 s0 = *(const float2*)(g1);
    float2 s1 = *(const float2*)(g1 + 512);
    float2 s2 = *(const float2*)(g1 + 1024);
    giN0 = s0.x; giN3 = s0.y; giN1 = s1.x; giN4 = s1.y; giN2 = s2.x; giN5 = s2.y;
  }

  // ---- prologue: pollers fetch h_0 (parity 0, tag 0, ALL 16 fragments) ----
  if (!gthr) {
    const unsigned long long* base = hxt + pt * 2;
    uint4v r[16];
    unsigned pend = 0xFFFFu;
    do {
#pragma unroll
      for (int m = 0; m < 16; ++m)
        if (pend & (1u << m))
          asm volatile("global_load_dwordx4 %0, %1, off sc0 sc1"
                       : "=v"(r[m]) : "v"(base + m * 256));
      asm volatile("s_waitcnt vmcnt(0)" ::: "memory");
      __builtin_amdgcn_sched_barrier(0);
#pragma unroll
      for (int m = 0; m < 16; ++m)
        if ((pend & (1u << m)) && r[m].y == 0u && r[m].w == 0u) {
          *(uint2*)&afl[pt * 2 + m * 256] = make_uint2(r[m].x, r[m].z);
          pend &= ~(1u << m);
        }
    } while (pend);
  }
  wg_barrier();

  for (int t = 0; t < T_; ++t) {
    // ---- phase 1: all 6 waves MFMA gh = h_t @ Whh_slice^T ----
    f32x4 a0 = (f32x4)0.f, a1 = (f32x4)0.f, a2 = (f32x4)0.f, a3 = (f32x4)0.f;
#pragma unroll
    for (int s = 0; s < 4; ++s) {
      union { uint4v u; short8 s8; } c0, c1, c2, c3;
      c0.u = *(const uint4v*)&afl[((4 * s + 0) * 64 + l) * 4];
      c1.u = *(const uint4v*)&afl[((4 * s + 1) * 64 + l) * 4];
      c2.u = *(const uint4v*)&afl[((4 * s + 2) * 64 + l) * 4];
      c3.u = *(const uint4v*)&afl[((4 * s + 3) * 64 + l) * 4];
      a0 = __builtin_amdgcn_mfma_f32_16x16x32_bf16(c0.s8, bfrag[4 * s + 0], a0, 0, 0, 0);
      a1 = __builtin_amdgcn_mfma_f32_16x16x32_bf16(c1.s8, bfrag[4 * s + 1], a1, 0, 0, 0);
      a2 = __builtin_amdgcn_mfma_f32_16x16x32_bf16(c2.s8, bfrag[4 * s + 2], a2, 0, 0, 0);
      a3 = __builtin_amdgcn_mfma_f32_16x16x32_bf16(c3.s8, bfrag[4 * s + 3], a3, 0, 0, 0);
    }
#pragma unroll
    for (int j = 0; j < 4; ++j)
      gh_lds[v * 256 + (fq * 4 + j) * 16 + fr] = a0[j] + a1[j] + a2[j] + a3[j] + bo;
    wg_barrier();

    // ---- phase 2: gates+store (waves 0-3) || poll t+1 (waves 4-5) ----
    if (gthr) {
      const int hh = jl >> 4, c = jl & 15;
      float2 rr = *(const float2*)&gh_lds[(0 + hh) * 256 + b * 16 + c];
      float2 zz = *(const float2*)&gh_lds[(2 + hh) * 256 + b * 16 + c];
      float2 nn = *(const float2*)&gh_lds[(4 + hh) * 256 + b * 16 + c];
      float rgA = __builtin_amdgcn_rcpf(1.f + __expf(-(giC0 + rr.x)));
      float rgB = __builtin_amdgcn_rcpf(1.f + __expf(-(giC3 + rr.y)));
      float zgA = __builtin_amdgcn_rcpf(1.f + __expf(-(giC1 + zz.x)));
      float zgB = __builtin_amdgcn_rcpf(1.f + __expf(-(giC4 + zz.y)));
      float eA = __expf(2.f * (giC2 + rgA * nn.x));
      float eB = __expf(2.f * (giC5 + rgB * nn.y));
      float ngA = 1.f - 2.f * __builtin_amdgcn_rcpf(eA + 1.f);
      float ngB = 1.f - 2.f * __builtin_amdgcn_rcpf(eB + 1.f);
      hA = (1.f - zgA) * ngA + zgA * hA;
      hB = (1.f - zgB) * ngB + zgB * hB;
      unsigned pk = (unsigned)bf16rn(hA) | ((unsigned)bf16rn(hB) << 16);
      const int fl = (b | ((jp >> 2) << 4)) * 4 + (jp & 3);  // lane*4+k
      if (t + 1 < T_) {
        // tagged 8B agent store = data + release flag in one transaction
        unsigned long long payload =
            (unsigned long long)pk | ((unsigned long long)(unsigned)(t + 1) << 32);
        unsigned long long* dst =
            hxt + ((size_t)((t + 1) & 1) * 16 + w) * 256 + fl;
        __hip_atomic_store(dst, payload, __ATOMIC_RELAXED, __HIP_MEMORY_SCOPE_AGENT);
        // own fragment straight to LDS (pollers skip line m == w)
        afl[w * 256 + fl] = pk;
      }
      // off-critical-path: fp32 h for fc3; shift gi pipeline; prefetch gi[t+2]
      *(float2*)(hsbuf + ((size_t)t * 16 + b) * 512 + w * 32 + jl) =
          make_float2(hA, hB);
      giC0 = giN0; giC1 = giN1; giC2 = giN2;
      giC3 = giN3; giC4 = giN4; giC5 = giN5;
      if (t + 2 < T_) {
        const float* gb = gi + ((size_t)(t + 2) * 16 + b) * 1536 + w * 32 + jl;
        float2 r0 = *(const float2*)(gb);
        float2 r1 = *(const float2*)(gb + 512);
        float2 r2 = *(const float2*)(gb + 1024);
        giN0 = r0.x; giN3 = r0.y; giN1 = r1.x; giN4 = r1.y; giN2 = r2.x; giN5 = r2.y;
      }
    } else if (t + 1 < T_) {
      const unsigned long long* base =
          hxt + (size_t)((t + 1) & 1) * 4096 + pt * 2;
      const unsigned tag = (unsigned)(t + 1);
      uint4v r[16];
      unsigned pend = 0xFFFFu & ~(1u << w);   // own fragment arrives via LDS
      do {
#pragma unroll
        for (int m = 0; m < 16; ++m)
          if (pend & (1u << m))
            asm volatile("global_load_dwordx4 %0, %1, off sc0 sc1"
                         : "=v"(r[m]) : "v"(base + m * 256));
        asm volatile("s_waitcnt vmcnt(0)" ::: "memory");
        __builtin_amdgcn_sched_barrier(0);
#pragma unroll
        for (int m = 0; m < 16; ++m)
          if ((pend & (1u << m)) && r[m].y == tag && r[m].w == tag) {
            *(uint2*)&afl[pt * 2 + m * 256] = make_uint2(r[m].x, r[m].z);
            pend &= ~(1u << m);
          }
      } while (pend);
    }
    wg_barrier();
  }
}

// ---------------- fc3 ----------------
__global__ __launch_bounds__(256) void fc3_kernel(
    const float* __restrict__ hs, const float* __restrict__ w3,
    const float* __restrict__ b3, float* __restrict__ out) {
  __shared__ float w[512];
  const int tid = threadIdx.x;
  w[tid] = w3[tid];
  w[tid + 256] = w3[tid + 256];
  __syncthreads();
  const int gidx = blockIdx.x * 256 + tid;  // b*512 + t
  const int b = gidx >> 9, t = gidx & 511;
  const float4* hr = (const float4*)(hs + ((size_t)t * 16 + b) * 512);
  const float4* wr = (const float4*)w;
  float acc = 0.f;
#pragma unroll 8
  for (int kc = 0; kc < 128; ++kc) {
    float4 h = hr[kc], ww = wr[kc];
    acc += h.x * ww.x + h.y * ww.y + h.z * ww.z + h.w * ww.w;
  }
  out[gidx] = acc + b3[0];
}

// ---------------------------------------------------------------------------
extern "C" void kernel_launch(void* const* d_in, const int* in_sizes, int n_in,
                              void* d_out, int out_size, void* d_ws,
                              size_t ws_size, hipStream_t stream) {
  const float* phone = (const float*)d_in[0];
  const float* h0    = (const float*)d_in[1];
  const float* w1    = (const float*)d_in[2];
  const float* b1    = (const float*)d_in[3];
  const float* w2    = (const float*)d_in[4];
  const float* b2    = (const float*)d_in[5];
  const float* fc1w  = (const float*)d_in[6];
  const float* fc1b  = (const float*)d_in[7];
  const float* fc2w  = (const float*)d_in[8];
  const float* fc2b  = (const float*)d_in[9];
  const float* wih   = (const float*)d_in[10];
  const float* whh   = (const float*)d_in[11];
  const float* bih   = (const float*)d_in[12];
  const float* bhh   = (const float*)d_in[13];
  const float* w3    = (const float*)d_in[14];
  const float* b3    = (const float*)d_in[15];
  float* out = (float*)d_out;

  char* ws = (char*)d_ws;
  ushort* out1b = (ushort*)(ws + 0);            // 41,943,040
  ushort* feat2 = (ushort*)(ws + 41943040);     // 25,165,824
  ushort* feat3 = (ushort*)(ws + 67108864);     // 16,777,216 (dead after fc2)
  ushort* feat4 = (ushort*)(ws + 83886080);     //  8,388,608
  float*  gibuf = (float*) (ws + 92274688);     // 50,331,648  [t][b][1536]
  float*  hsbuf = (float*) (ws + 142606336);    // 16,777,216  [t][b][512]
  ushort* w2b   = (ushort*)(ws + 159383552);    //    589,824
  ushort* fc1wb = (ushort*)(ws + 159973376);    //  3,145,728
  ushort* fc2wb = (ushort*)(ws + 163119104);    //  1,048,576
  ushort* wihb  = (ushort*)(ws + 164167680);    //  1,572,864
  // tagged h-exchange buffer (2 x 32KB parity) overlaps the dead feat3 region
  unsigned long long* hxt = (unsigned long long*)(ws + 67108864);

  f32_to_bf16<<<288, 256, 0, stream>>>(w2, w2b, 73728);
  f32_to_bf16<<<1536, 256, 0, stream>>>(fc1w, fc1wb, 393216);
  f32_to_bf16<<<512, 256, 0, stream>>>(fc2w, fc2wb, 131072);
  f32_to_bf16<<<768, 256, 0, stream>>>(wih, wihb, 196608);

  conv1_kernel<<<1024, 256, 0, stream>>>(phone, w1, b1, out1b);
  gemm_bf16<1, 1><<<dim3(768, 2), 256, 0, stream>>>(out1b, w2b, b2, feat2, 1152, 0, 0);
  gemm_bf16<0, 0><<<dim3(64, 8), 256, 0, stream>>>(feat2, fc1wb, fc1b, feat3, 1536, 1536, 1024);
  gemm_bf16<0, 0><<<dim3(64, 4), 256, 0, stream>>>(feat3, fc2wb, fc2b, feat4, 1024, 1024, 512);
  gemm_bf16<0, 2><<<dim3(64, 12), 256, 0, stream>>>(feat4, wihb, bih, gibuf, 512, 512, 1536);

  // clear BOTH parity tag buffers (replay-safe), stage h0, run recurrence
  hipMemsetAsync(hxt, 0, 65536, stream);
  stage_h0<<<1, 256, 0, stream>>>(h0, hxt);
  gru_persistent<<<16, 384, 0, stream>>>(h0, gibuf, whh, bhh, hsbuf, hxt);

  fc3_kernel<<<32, 256, 0, stream>>>(hsbuf, w3, b3, out);
}

// Round 11
// 1699.912 us; speedup vs baseline: 1.1085x; 1.1085x over previous
//
#include <hip/hip_runtime.h>
#include <hip/hip_bf16.h>
#include <math.h>
#include <stdint.h>

typedef __attribute__((ext_vector_type(8))) short short8;
typedef __attribute__((ext_vector_type(4))) float f32x4;
typedef __attribute__((ext_vector_type(4))) unsigned int uint4v;

#define T_ 512

__device__ __forceinline__ unsigned short bf16rn(float f) {
  union { float f; unsigned u; } x; x.f = f;
  unsigned r = x.u + 0x7FFF + ((x.u >> 16) & 1);
  return (unsigned short)(r >> 16);
}

__device__ __forceinline__ void gload16(const void* gsrc, void* ldst) {
  __builtin_amdgcn_global_load_lds(
      (const __attribute__((address_space(1))) unsigned int*)gsrc,
      (__attribute__((address_space(3))) unsigned int*)ldst, 16, 0, 0);
}

// raw barrier: LDS-visibility only (lgkmcnt), NO vmcnt drain -> the gate
// threads' gi prefetch / hsbuf / hxt stores stay off the critical path.
// (r9 validated correctness of this barrier; r9's regression was its
// progressive-poll VALU overhead, not the barrier.)
__device__ __forceinline__ void wg_barrier() {
  __builtin_amdgcn_sched_barrier(0);
  asm volatile("s_waitcnt lgkmcnt(0)" ::: "memory");
  __builtin_amdgcn_sched_barrier(0);
  __builtin_amdgcn_s_barrier();
  __builtin_amdgcn_sched_barrier(0);
}

// ---------------- conv1 + pool (fp32 math, bf16 out), 8 frames/block ----------------
__global__ __launch_bounds__(256) void conv1_kernel(
    const float* __restrict__ phone, const float* __restrict__ w1,
    const float* __restrict__ b1, ushort* __restrict__ out1b) {
  __shared__ float ws[128 * 77];
  __shared__ float bs[128];
  __shared__ float xs[8][7][52];
  const int tid = threadIdx.x;
  const int n0 = blockIdx.x * 8;
  for (int idx = tid; idx < 9856; idx += 256) ws[idx] = w1[idx];
  if (tid < 128) bs[tid] = b1[tid];
  for (int idx = tid; idx < 2800; idx += 256) {
    int fi = idx / 350, r = idx - fi * 350;
    int ll = r / 7, c = r - ll * 7;
    xs[fi][c][ll] = phone[(size_t)(n0 + fi) * 350 + r];
  }
  __syncthreads();

  const int o = tid >> 1, ph = tid & 1;
  const float* wo = ws + o * 77;
  const float bb = bs[o];
  for (int fi = 0; fi < 8; ++fi) {
    float acc0[10], acc1[10];
#pragma unroll
    for (int q = 0; q < 10; ++q) { acc0[q] = 0.f; acc1[q] = 0.f; }
    for (int i = 0; i < 7; ++i) {
      float wr[11];
#pragma unroll
      for (int k = 0; k < 11; ++k) wr[k] = wo[i * 11 + k];
#pragma unroll
      for (int q = 0; q < 10; ++q) {
        int p = ph * 10 + q;
        int base = 2 * p;
        float xv[12];
#pragma unroll
        for (int j = 0; j < 12; ++j) xv[j] = xs[fi][i][base + j];
        float s0 = 0.f, s1 = 0.f;
#pragma unroll
        for (int k = 0; k < 11; ++k) {
          s0 += xv[k] * wr[k];
          s1 += xv[k + 1] * wr[k];
        }
        acc0[q] += s0;
        acc1[q] += s1;
      }
    }
#pragma unroll
    for (int q = 0; q < 10; ++q) {
      int p = ph * 10 + q;
      out1b[((size_t)(n0 + fi) * 128 + o) * 20 + p] =
          bf16rn(fmaxf(acc0[q], acc1[q]) + bb);
    }
  }
}

// ---------------- fp32 -> bf16 convert ----------------
__global__ __launch_bounds__(256) void f32_to_bf16(
    const float* __restrict__ src, ushort* __restrict__ dst, int n4) {
  int i = blockIdx.x * 256 + threadIdx.x;
  if (i < n4) {
    float4 v = ((const float4*)src)[i];
    ushort4 o;
    o.x = bf16rn(v.x); o.y = bf16rn(v.y); o.z = bf16rn(v.z); o.w = bf16rn(v.w);
    ((ushort4*)dst)[i] = o;
  }
}

// ---------------- stage h0 -> tagged bf16 fragments (parity-0 buffer, tag 0) ----------------
__global__ __launch_bounds__(256) void stage_h0(
    const float* __restrict__ h0, unsigned long long* __restrict__ hxt) {
  const int tid = threadIdx.x;
  const int b = tid >> 4, x = tid & 15;
#pragma unroll
  for (int q = 0; q < 16; ++q) {
    int d = (x + q * 16) * 2;
    int s = d >> 5, fqq = (d >> 3) & 3, k = (d & 7) >> 1;
    int lane = b | (fqq << 4);
    float2 h2 = *(const float2*)(h0 + (size_t)b * 512 + d);
    unsigned pk = (unsigned)bf16rn(h2.x) | ((unsigned)bf16rn(h2.y) << 16);
    hxt[((size_t)s * 64 + lane) * 4 + k] = (unsigned long long)pk;  // tag = 0
  }
}

// ---------------- bf16 MFMA GEMM: C = A @ W^T + bias ----------------
template <int AM, int EM>
__global__ __launch_bounds__(256) void gemm_bf16(
    const ushort* __restrict__ A, const ushort* __restrict__ W,
    const float* __restrict__ bias, void* __restrict__ Cout,
    int K, int lda, int ldc) {
  __shared__ ushort As[128 * 64];
  __shared__ ushort Bs[128 * 64];
  __shared__ ushort tbl[1152];
  const int tid = threadIdx.x;
  const int l = tid & 63, wv = tid >> 6;
  const int wr = wv >> 1, wc = wv & 1;
  const int fr = l & 15, fq = l >> 4;
  const int bm0 = blockIdx.x * 128, bn0 = blockIdx.y * 128;

  if (AM == 1) {
    for (int idx = tid; idx < 1152; idx += 256) {
      int i2 = idx / 9, kp = idx - i2 * 9;
      tbl[idx] = (ushort)(i2 * 20 + kp);
    }
    __syncthreads();
  }

  f32x4 acc[4][4];
#pragma unroll
  for (int mi = 0; mi < 4; ++mi)
#pragma unroll
    for (int ni = 0; ni < 4; ++ni) acc[mi][ni] = (f32x4)0.f;

  const int pr8 = l >> 3;
  const int pc = l & 7;
  const int nkt = K >> 6;
  for (int kt = 0; kt < nkt; ++kt) {
    const int k0 = kt << 6;
#pragma unroll
    for (int i = 0; i < 4; ++i) {
      int q = wv * 4 + i;
      int prow = q * 8 + pr8;
      int lc = pc ^ (prow & 7);
      gload16(W + (size_t)(bn0 + prow) * K + k0 + lc * 8, &Bs[q * 512]);
    }
    if (AM == 0) {
#pragma unroll
      for (int i = 0; i < 4; ++i) {
        int q = wv * 4 + i;
        int prow = q * 8 + pr8;
        int lc = pc ^ (prow & 7);
        gload16(A + (size_t)(bm0 + prow) * lda + k0 + lc * 8, &As[q * 512]);
      }
    } else {
#pragma unroll
      for (int q = 0; q < 16; ++q) {
        int idx = tid + q * 256;
        int row = idx >> 5, c0 = (idx & 31) * 2;
        int m = bm0 + row;
        int n = m / 12, pos = m - n * 12;
        int kk = k0 + c0;
        const ushort* an = A + (size_t)n * 2560 + pos;
        uint e0 = an[tbl[kk]];
        uint e1 = an[tbl[kk + 1]];
        *(uint*)&As[row * 64 + (((c0 >> 3) ^ (row & 7)) << 3) + (c0 & 7)] =
            e0 | (e1 << 16);
      }
    }
    __syncthreads();
#pragma unroll
    for (int ks = 0; ks < 2; ++ks) {
      short8 af[4], bfr[4];
#pragma unroll
      for (int mi = 0; mi < 4; ++mi) {
        int row = wr * 64 + mi * 16 + fr;
        af[mi] = *(const short8*)&As[row * 64 + (((ks * 4 + fq) ^ (row & 7)) << 3)];
      }
#pragma unroll
      for (int ni = 0; ni < 4; ++ni) {
        int row = wc * 64 + ni * 16 + fr;
        bfr[ni] = *(const short8*)&Bs[row * 64 + (((ks * 4 + fq) ^ (row & 7)) << 3)];
      }
#pragma unroll
      for (int mi = 0; mi < 4; ++mi)
#pragma unroll
        for (int ni = 0; ni < 4; ++ni)
          acc[mi][ni] = __builtin_amdgcn_mfma_f32_16x16x32_bf16(
              af[mi], bfr[ni], acc[mi][ni], 0, 0, 0);
    }
    __syncthreads();
  }

#pragma unroll
  for (int ni = 0; ni < 4; ++ni) {
    int col = bn0 + wc * 64 + ni * 16 + fr;
    float bv = bias[col];
#pragma unroll
    for (int mi = 0; mi < 4; ++mi) {
      int mbase = bm0 + wr * 64 + mi * 16 + fq * 4;
      if (EM == 0) {
        ushort* C = (ushort*)Cout;
#pragma unroll
        for (int j = 0; j < 4; ++j)
          C[(size_t)(mbase + j) * ldc + col] = bf16rn(acc[mi][ni][j] + bv);
      } else if (EM == 1) {
        ushort* C = (ushort*)Cout;
#pragma unroll
        for (int j = 0; j < 4; j += 2) {
          int m = mbase + j;
          int n = m / 12, pos = m - n * 12;
          float v = fmaxf(acc[mi][ni][j], acc[mi][ni][j + 1]) + bv;
          C[(size_t)n * 1536 + col * 6 + (pos >> 1)] = bf16rn(v);
        }
      } else {
        float* C = (float*)Cout;
#pragma unroll
        for (int j = 0; j < 4; ++j) {
          int m = mbase + j;
          int b = m >> 9, tt = m & 511;
          C[((size_t)tt * 16 + b) * 1536 + col] = acc[mi][ni][j] + bv;
        }
      }
    }
  }
}

// ---------------- persistent GRU: r8 structure + lgkm-only barriers ----------------
// 16 WGs x 384 thr.  Waves 0-3 = gate/producer (also MFMA); waves 4-5 =
// pollers (also MFMA).  Per step: phase1 = all-wave MFMA; phase2 = {gates +
// tagged agent store for t+1} CONCURRENT WITH {pollers batch-spin on
// parity(t+1) tags via sc0 sc1 and deposit into LDS}.  Barriers are raw
// s_barrier + lgkmcnt(0) only: no vmcnt drain of gi prefetch / stores.
__global__ __launch_bounds__(384) void gru_persistent(
    const float* __restrict__ h0, const float* __restrict__ gi,
    const float* __restrict__ whh, const float* __restrict__ bhh,
    float* __restrict__ hsbuf, unsigned long long* __restrict__ hxt) {
  __shared__ float gh_lds[6 * 256];
  __shared__ unsigned afl[16 * 64 * 4];  // 16KB: [s][lane][4] pk words
  const int tid = threadIdx.x;
  const int w = blockIdx.x;              // 0..15
  const int l = tid & 63, v = tid >> 6;  // wave 0..5
  const int fr = l & 15, fq = l >> 4;
  const int g = v >> 1, half = v & 1;
  const int o = g * 512 + w * 32 + half * 16 + fr;

  // persistent Whh B-fragments (64 VGPR, all waves)
  short8 bfrag[16];
#pragma unroll
  for (int s = 0; s < 16; ++s) {
    const float* wp = whh + (size_t)o * 512 + s * 32 + fq * 8;
    float4 w0 = *(const float4*)wp;
    float4 w1 = *(const float4*)(wp + 4);
    short8 bb;
    bb[0] = (short)bf16rn(w0.x); bb[1] = (short)bf16rn(w0.y);
    bb[2] = (short)bf16rn(w0.z); bb[3] = (short)bf16rn(w0.w);
    bb[4] = (short)bf16rn(w1.x); bb[5] = (short)bf16rn(w1.y);
    bb[6] = (short)bf16rn(w1.z); bb[7] = (short)bf16rn(w1.w);
    bfrag[s] = bb;
  }
  const float bo = bhh[o];

  // gate-thread persistent state (threads 0..255): pair (jl, jl+1)
  const int b = tid >> 4, jp = tid & 15, jl = jp * 2;
  const bool gthr = (tid < 256);
  const int pt = tid - 256;              // poller index 0..127 (waves 4,5)
  float hA = 0.f, hB = 0.f;
  float giC0 = 0.f, giC1 = 0.f, giC2 = 0.f, giC3 = 0.f, giC4 = 0.f, giC5 = 0.f;
  float giN0 = 0.f, giN1 = 0.f, giN2 = 0.f, giN3 = 0.f, giN4 = 0.f, giN5 = 0.f;
  if (gthr) {
    float2 h2 = *(const float2*)(h0 + (size_t)b * 512 + w * 32 + jl);
    hA = h2.x; hB = h2.y;
    const float* g0 = gi + (size_t)b * 1536 + w * 32 + jl;           // gi[0]
    float2 r0 = *(const float2*)(g0);
    float2 r1 = *(const float2*)(g0 + 512);
    float2 r2 = *(const float2*)(g0 + 1024);
    giC0 = r0.x; giC3 = r0.y; giC1 = r1.x; giC4 = r1.y; giC2 = r2.x; giC5 = r2.y;
    const float* g1 = gi + (size_t)(16 + b) * 1536 + w * 32 + jl;    // gi[1]
    float2 s0 = *(const float2*)(g1);
    float2 s1 = *(const float2*)(g1 + 512);
    float2 s2 = *(const float2*)(g1 + 1024);
    giN0 = s0.x; giN3 = s0.y; giN1 = s1.x; giN4 = s1.y; giN2 = s2.x; giN5 = s2.y;
  }

  // ---- prologue: pollers fetch h_0 (parity 0, tag 0) ----
  if (!gthr) {
    const unsigned long long* base = hxt + pt * 2;
    uint4v r[16];
    for (;;) {
#pragma unroll
      for (int m = 0; m < 16; ++m)
        asm volatile("global_load_dwordx4 %0, %1, off sc0 sc1"
                     : "=v"(r[m]) : "v"(base + m * 256));
      asm volatile("s_waitcnt vmcnt(0)" ::: "memory");
      __builtin_amdgcn_sched_barrier(0);
      bool ok = true;
#pragma unroll
      for (int m = 0; m < 16; ++m)
        ok = ok & (r[m].y == 0u) & (r[m].w == 0u);
      if (ok) break;
    }
#pragma unroll
    for (int m = 0; m < 16; ++m)
      *(uint2*)&afl[pt * 2 + m * 256] = make_uint2(r[m].x, r[m].z);
  }
  wg_barrier();

  for (int t = 0; t < T_; ++t) {
    // ---- phase 1: all 6 waves MFMA gh = h_t @ Whh_slice^T ----
    f32x4 a0 = (f32x4)0.f, a1 = (f32x4)0.f, a2 = (f32x4)0.f, a3 = (f32x4)0.f;
#pragma unroll
    for (int s = 0; s < 4; ++s) {
      union { uint4v u; short8 s8; } c0, c1, c2, c3;
      c0.u = *(const uint4v*)&afl[((4 * s + 0) * 64 + l) * 4];
      c1.u = *(const uint4v*)&afl[((4 * s + 1) * 64 + l) * 4];
      c2.u = *(const uint4v*)&afl[((4 * s + 2) * 64 + l) * 4];
      c3.u = *(const uint4v*)&afl[((4 * s + 3) * 64 + l) * 4];
      a0 = __builtin_amdgcn_mfma_f32_16x16x32_bf16(c0.s8, bfrag[4 * s + 0], a0, 0, 0, 0);
      a1 = __builtin_amdgcn_mfma_f32_16x16x32_bf16(c1.s8, bfrag[4 * s + 1], a1, 0, 0, 0);
      a2 = __builtin_amdgcn_mfma_f32_16x16x32_bf16(c2.s8, bfrag[4 * s + 2], a2, 0, 0, 0);
      a3 = __builtin_amdgcn_mfma_f32_16x16x32_bf16(c3.s8, bfrag[4 * s + 3], a3, 0, 0, 0);
    }
#pragma unroll
    for (int j = 0; j < 4; ++j)
      gh_lds[v * 256 + (fq * 4 + j) * 16 + fr] = a0[j] + a1[j] + a2[j] + a3[j] + bo;
    wg_barrier();

    // ---- phase 2: gates+store (waves 0-3) || poll t+1 (waves 4-5) ----
    if (gthr) {
      const int hh = jl >> 4, c = jl & 15;
      float2 rr = *(const float2*)&gh_lds[(0 + hh) * 256 + b * 16 + c];
      float2 zz = *(const float2*)&gh_lds[(2 + hh) * 256 + b * 16 + c];
      float2 nn = *(const float2*)&gh_lds[(4 + hh) * 256 + b * 16 + c];
      float rgA = __builtin_amdgcn_rcpf(1.f + __expf(-(giC0 + rr.x)));
      float rgB = __builtin_amdgcn_rcpf(1.f + __expf(-(giC3 + rr.y)));
      float zgA = __builtin_amdgcn_rcpf(1.f + __expf(-(giC1 + zz.x)));
      float zgB = __builtin_amdgcn_rcpf(1.f + __expf(-(giC4 + zz.y)));
      float eA = __expf(2.f * (giC2 + rgA * nn.x));
      float eB = __expf(2.f * (giC5 + rgB * nn.y));
      float ngA = 1.f - 2.f * __builtin_amdgcn_rcpf(eA + 1.f);
      float ngB = 1.f - 2.f * __builtin_amdgcn_rcpf(eB + 1.f);
      hA = (1.f - zgA) * ngA + zgA * hA;
      hB = (1.f - zgB) * ngB + zgB * hB;
      // tagged 8B agent store = data + release flag in one transaction
      if (t + 1 < T_) {
        unsigned pk = (unsigned)bf16rn(hA) | ((unsigned)bf16rn(hB) << 16);
        unsigned long long payload =
            (unsigned long long)pk | ((unsigned long long)(unsigned)(t + 1) << 32);
        unsigned long long* dst =
            hxt + (((size_t)((t + 1) & 1) * 16 + w) * 64 + (b | ((jp >> 2) << 4))) * 4 +
            (jp & 3);
        __hip_atomic_store(dst, payload, __ATOMIC_RELAXED, __HIP_MEMORY_SCOPE_AGENT);
      }
      // off-critical-path: fp32 h for fc3; shift gi pipeline; prefetch gi[t+2]
      *(float2*)(hsbuf + ((size_t)t * 16 + b) * 512 + w * 32 + jl) =
          make_float2(hA, hB);
      giC0 = giN0; giC1 = giN1; giC2 = giN2;
      giC3 = giN3; giC4 = giN4; giC5 = giN5;
      if (t + 2 < T_) {
        const float* gb = gi + ((size_t)(t + 2) * 16 + b) * 1536 + w * 32 + jl;
        float2 r0 = *(const float2*)(gb);
        float2 r1 = *(const float2*)(gb + 512);
        float2 r2 = *(const float2*)(gb + 1024);
        giN0 = r0.x; giN3 = r0.y; giN1 = r1.x; giN4 = r1.y; giN2 = r2.x; giN5 = r2.y;
      }
    } else if (t + 1 < T_) {
      const unsigned long long* base =
          hxt + (size_t)((t + 1) & 1) * 4096 + pt * 2;
      const unsigned tag = (unsigned)(t + 1);
      uint4v r[16];
      for (;;) {
#pragma unroll
        for (int m = 0; m < 16; ++m)
          asm volatile("global_load_dwordx4 %0, %1, off sc0 sc1"
                       : "=v"(r[m]) : "v"(base + m * 256));
        asm volatile("s_waitcnt vmcnt(0)" ::: "memory");
        __builtin_amdgcn_sched_barrier(0);
        bool ok = true;
#pragma unroll
        for (int m = 0; m < 16; ++m)
          ok = ok & (r[m].y == tag) & (r[m].w == tag);
        if (ok) break;
      }
#pragma unroll
      for (int m = 0; m < 16; ++m)
        *(uint2*)&afl[pt * 2 + m * 256] = make_uint2(r[m].x, r[m].z);
    }
    wg_barrier();
  }
}

// ---------------- fc3 ----------------
__global__ __launch_bounds__(256) void fc3_kernel(
    const float* __restrict__ hs, const float* __restrict__ w3,
    const float* __restrict__ b3, float* __restrict__ out) {
  __shared__ float w[512];
  const int tid = threadIdx.x;
  w[tid] = w3[tid];
  w[tid + 256] = w3[tid + 256];
  __syncthreads();
  const int gidx = blockIdx.x * 256 + tid;  // b*512 + t
  const int b = gidx >> 9, t = gidx & 511;
  const float4* hr = (const float4*)(hs + ((size_t)t * 16 + b) * 512);
  const float4* wr = (const float4*)w;
  float acc = 0.f;
#pragma unroll 8
  for (int kc = 0; kc < 128; ++kc) {
    float4 h = hr[kc], ww = wr[kc];
    acc += h.x * ww.x + h.y * ww.y + h.z * ww.z + h.w * ww.w;
  }
  out[gidx] = acc + b3[0];
}

// ---------------------------------------------------------------------------
extern "C" void kernel_launch(void* const* d_in, const int* in_sizes, int n_in,
                              void* d_out, int out_size, void* d_ws,
                              size_t ws_size, hipStream_t stream) {
  const float* phone = (const float*)d_in[0];
  const float* h0    = (const float*)d_in[1];
  const float* w1    = (const float*)d_in[2];
  const float* b1    = (const float*)d_in[3];
  const float* w2    = (const float*)d_in[4];
  const float* b2    = (const float*)d_in[5];
  const float* fc1w  = (const float*)d_in[6];
  const float* fc1b  = (const float*)d_in[7];
  const float* fc2w  = (const float*)d_in[8];
  const float* fc2b  = (const float*)d_in[9];
  const float* wih   = (const float*)d_in[10];
  const float* whh   = (const float*)d_in[11];
  const float* bih   = (const float*)d_in[12];
  const float* bhh   = (const float*)d_in[13];
  const float* w3    = (const float*)d_in[14];
  const float* b3    = (const float*)d_in[15];
  float* out = (float*)d_out;

  char* ws = (char*)d_ws;
  ushort* out1b = (ushort*)(ws + 0);            // 41,943,040
  ushort* feat2 = (ushort*)(ws + 41943040);     // 25,165,824
  ushort* feat3 = (ushort*)(ws + 67108864);     // 16,777,216 (dead after fc2)
  ushort* feat4 = (ushort*)(ws + 83886080);     //  8,388,608
  float*  gibuf = (float*) (ws + 92274688);     // 50,331,648  [t][b][1536]
  float*  hsbuf = (float*) (ws + 142606336);    // 16,777,216  [t][b][512]
  ushort* w2b   = (ushort*)(ws + 159383552);    //    589,824
  ushort* fc1wb = (ushort*)(ws + 159973376);    //  3,145,728
  ushort* fc2wb = (ushort*)(ws + 163119104);    //  1,048,576
  ushort* wihb  = (ushort*)(ws + 164167680);    //  1,572,864
  // tagged h-exchange buffer (2 x 32KB parity) overlaps the dead feat3 region
  unsigned long long* hxt = (unsigned long long*)(ws + 67108864);

  f32_to_bf16<<<288, 256, 0, stream>>>(w2, w2b, 73728);
  f32_to_bf16<<<1536, 256, 0, stream>>>(fc1w, fc1wb, 393216);
  f32_to_bf16<<<512, 256, 0, stream>>>(fc2w, fc2wb, 131072);
  f32_to_bf16<<<768, 256, 0, stream>>>(wih, wihb, 196608);

  conv1_kernel<<<1024, 256, 0, stream>>>(phone, w1, b1, out1b);
  gemm_bf16<1, 1><<<dim3(768, 2), 256, 0, stream>>>(out1b, w2b, b2, feat2, 1152, 0, 0);
  gemm_bf16<0, 0><<<dim3(64, 8), 256, 0, stream>>>(feat2, fc1wb, fc1b, feat3, 1536, 1536, 1024);
  gemm_bf16<0, 0><<<dim3(64, 4), 256, 0, stream>>>(feat3, fc2wb, fc2b, feat4, 1024, 1024, 512);
  gemm_bf16<0, 2><<<dim3(64, 12), 256, 0, stream>>>(feat4, wihb, bih, gibuf, 512, 512, 1536);

  // clear BOTH parity tag buffers (replay-safe), stage h0, run recurrence
  hipMemsetAsync(hxt, 0, 65536, stream);
  stage_h0<<<1, 256, 0, stream>>>(h0, hxt);
  gru_persistent<<<16, 384, 0, stream>>>(h0, gibuf, whh, bhh, hsbuf, hxt);

  fc3_kernel<<<32, 256, 0, stream>>>(hsbuf, w3, b3, out);
}

// Round 12
// 1495.333 us; speedup vs baseline: 1.2602x; 1.1368x over previous
//
#include <hip/hip_runtime.h>
#include <hip/hip_bf16.h>
#include <math.h>
#include <stdint.h>

typedef __attribute__((ext_vector_type(8))) short short8;
typedef __attribute__((ext_vector_type(4))) float f32x4;
typedef __attribute__((ext_vector_type(4))) unsigned int uint4v;

#define T_ 512

__device__ __forceinline__ unsigned short bf16rn(float f) {
  union { float f; unsigned u; } x; x.f = f;
  unsigned r = x.u + 0x7FFF + ((x.u >> 16) & 1);
  return (unsigned short)(r >> 16);
}

__device__ __forceinline__ void gload16(const void* gsrc, void* ldst) {
  __builtin_amdgcn_global_load_lds(
      (const __attribute__((address_space(1))) unsigned int*)gsrc,
      (__attribute__((address_space(3))) unsigned int*)ldst, 16, 0, 0);
}

// raw barrier: LDS-visibility only (lgkmcnt), NO vmcnt drain.
__device__ __forceinline__ void wg_barrier() {
  __builtin_amdgcn_sched_barrier(0);
  asm volatile("s_waitcnt lgkmcnt(0)" ::: "memory");
  __builtin_amdgcn_sched_barrier(0);
  __builtin_amdgcn_s_barrier();
  __builtin_amdgcn_sched_barrier(0);
}

// ---------------- conv1 + pool (fp32 math, bf16 out), 8 frames/block ----------------
__global__ __launch_bounds__(256) void conv1_kernel(
    const float* __restrict__ phone, const float* __restrict__ w1,
    const float* __restrict__ b1, ushort* __restrict__ out1b) {
  __shared__ float ws[128 * 77];
  __shared__ float bs[128];
  __shared__ float xs[8][7][52];
  const int tid = threadIdx.x;
  const int n0 = blockIdx.x * 8;
  for (int idx = tid; idx < 9856; idx += 256) ws[idx] = w1[idx];
  if (tid < 128) bs[tid] = b1[tid];
  for (int idx = tid; idx < 2800; idx += 256) {
    int fi = idx / 350, r = idx - fi * 350;
    int ll = r / 7, c = r - ll * 7;
    xs[fi][c][ll] = phone[(size_t)(n0 + fi) * 350 + r];
  }
  __syncthreads();

  const int o = tid >> 1, ph = tid & 1;
  const float* wo = ws + o * 77;
  const float bb = bs[o];
  for (int fi = 0; fi < 8; ++fi) {
    float acc0[10], acc1[10];
#pragma unroll
    for (int q = 0; q < 10; ++q) { acc0[q] = 0.f; acc1[q] = 0.f; }
    for (int i = 0; i < 7; ++i) {
      float wr[11];
#pragma unroll
      for (int k = 0; k < 11; ++k) wr[k] = wo[i * 11 + k];
#pragma unroll
      for (int q = 0; q < 10; ++q) {
        int p = ph * 10 + q;
        int base = 2 * p;
        float xv[12];
#pragma unroll
        for (int j = 0; j < 12; ++j) xv[j] = xs[fi][i][base + j];
        float s0 = 0.f, s1 = 0.f;
#pragma unroll
        for (int k = 0; k < 11; ++k) {
          s0 += xv[k] * wr[k];
          s1 += xv[k + 1] * wr[k];
        }
        acc0[q] += s0;
        acc1[q] += s1;
      }
    }
#pragma unroll
    for (int q = 0; q < 10; ++q) {
      int p = ph * 10 + q;
      out1b[((size_t)(n0 + fi) * 128 + o) * 20 + p] =
          bf16rn(fmaxf(acc0[q], acc1[q]) + bb);
    }
  }
}

// ---------------- fp32 -> bf16 convert ----------------
__global__ __launch_bounds__(256) void f32_to_bf16(
    const float* __restrict__ src, ushort* __restrict__ dst, int n4) {
  int i = blockIdx.x * 256 + threadIdx.x;
  if (i < n4) {
    float4 v = ((const float4*)src)[i];
    ushort4 o;
    o.x = bf16rn(v.x); o.y = bf16rn(v.y); o.z = bf16rn(v.z); o.w = bf16rn(v.w);
    ((ushort4*)dst)[i] = o;
  }
}

// ---------------- stage h0 -> tagged fragments, BOTH groups, parity 0, tag 0 ----------------
// hxt layout (8B words): [group][parity][frag s<16][word w<128]
//   w = (fq*8 + b8)*4 + p2;  b8=batch&7, fq=k-oct, p2=pair-in-oct
__global__ __launch_bounds__(256) void stage_h0(
    const float* __restrict__ h0, unsigned long long* __restrict__ hxt) {
  const int tid = threadIdx.x;
#pragma unroll
  for (int k = 0; k < 16; ++k) {
    int idx = tid + k * 256;             // 0..4095
    int g = idx >> 11, rem = idx & 2047;
    int s = rem >> 7, w_i = rem & 127;
    int b8 = (w_i >> 2) & 7, fqk = w_i >> 5, p2 = w_i & 3;
    int b = g * 8 + b8;
    int d = s * 32 + fqk * 8 + p2 * 2;
    float2 h2 = *(const float2*)(h0 + (size_t)b * 512 + d);
    unsigned pk = (unsigned)bf16rn(h2.x) | ((unsigned)bf16rn(h2.y) << 16);
    hxt[(size_t)g * 4096 + s * 128 + w_i] = (unsigned long long)pk;  // tag 0
  }
}

// ---------------- bf16 MFMA GEMM: C = A @ W^T + bias ----------------
template <int AM, int EM>
__global__ __launch_bounds__(256) void gemm_bf16(
    const ushort* __restrict__ A, const ushort* __restrict__ W,
    const float* __restrict__ bias, void* __restrict__ Cout,
    int K, int lda, int ldc) {
  __shared__ ushort As[128 * 64];
  __shared__ ushort Bs[128 * 64];
  __shared__ ushort tbl[1152];
  const int tid = threadIdx.x;
  const int l = tid & 63, wv = tid >> 6;
  const int wr = wv >> 1, wc = wv & 1;
  const int fr = l & 15, fq = l >> 4;
  const int bm0 = blockIdx.x * 128, bn0 = blockIdx.y * 128;

  if (AM == 1) {
    for (int idx = tid; idx < 1152; idx += 256) {
      int i2 = idx / 9, kp = idx - i2 * 9;
      tbl[idx] = (ushort)(i2 * 20 + kp);
    }
    __syncthreads();
  }

  f32x4 acc[4][4];
#pragma unroll
  for (int mi = 0; mi < 4; ++mi)
#pragma unroll
    for (int ni = 0; ni < 4; ++ni) acc[mi][ni] = (f32x4)0.f;

  const int pr8 = l >> 3;
  const int pc = l & 7;
  const int nkt = K >> 6;
  for (int kt = 0; kt < nkt; ++kt) {
    const int k0 = kt << 6;
#pragma unroll
    for (int i = 0; i < 4; ++i) {
      int q = wv * 4 + i;
      int prow = q * 8 + pr8;
      int lc = pc ^ (prow & 7);
      gload16(W + (size_t)(bn0 + prow) * K + k0 + lc * 8, &Bs[q * 512]);
    }
    if (AM == 0) {
#pragma unroll
      for (int i = 0; i < 4; ++i) {
        int q = wv * 4 + i;
        int prow = q * 8 + pr8;
        int lc = pc ^ (prow & 7);
        gload16(A + (size_t)(bm0 + prow) * lda + k0 + lc * 8, &As[q * 512]);
      }
    } else {
#pragma unroll
      for (int q = 0; q < 16; ++q) {
        int idx = tid + q * 256;
        int row = idx >> 5, c0 = (idx & 31) * 2;
        int m = bm0 + row;
        int n = m / 12, pos = m - n * 12;
        int kk = k0 + c0;
        const ushort* an = A + (size_t)n * 2560 + pos;
        uint e0 = an[tbl[kk]];
        uint e1 = an[tbl[kk + 1]];
        *(uint*)&As[row * 64 + (((c0 >> 3) ^ (row & 7)) << 3) + (c0 & 7)] =
            e0 | (e1 << 16);
      }
    }
    __syncthreads();
#pragma unroll
    for (int ks = 0; ks < 2; ++ks) {
      short8 af[4], bfr[4];
#pragma unroll
      for (int mi = 0; mi < 4; ++mi) {
        int row = wr * 64 + mi * 16 + fr;
        af[mi] = *(const short8*)&As[row * 64 + (((ks * 4 + fq) ^ (row & 7)) << 3)];
      }
#pragma unroll
      for (int ni = 0; ni < 4; ++ni) {
        int row = wc * 64 + ni * 16 + fr;
        bfr[ni] = *(const short8*)&Bs[row * 64 + (((ks * 4 + fq) ^ (row & 7)) << 3)];
      }
#pragma unroll
      for (int mi = 0; mi < 4; ++mi)
#pragma unroll
        for (int ni = 0; ni < 4; ++ni)
          acc[mi][ni] = __builtin_amdgcn_mfma_f32_16x16x32_bf16(
              af[mi], bfr[ni], acc[mi][ni], 0, 0, 0);
    }
    __syncthreads();
  }

#pragma unroll
  for (int ni = 0; ni < 4; ++ni) {
    int col = bn0 + wc * 64 + ni * 16 + fr;
    float bv = bias[col];
#pragma unroll
    for (int mi = 0; mi < 4; ++mi) {
      int mbase = bm0 + wr * 64 + mi * 16 + fq * 4;
      if (EM == 0) {
        ushort* C = (ushort*)Cout;
#pragma unroll
        for (int j = 0; j < 4; ++j)
          C[(size_t)(mbase + j) * ldc + col] = bf16rn(acc[mi][ni][j] + bv);
      } else if (EM == 1) {
        ushort* C = (ushort*)Cout;
#pragma unroll
        for (int j = 0; j < 4; j += 2) {
          int m = mbase + j;
          int n = m / 12, pos = m - n * 12;
          float v = fmaxf(acc[mi][ni][j], acc[mi][ni][j + 1]) + bv;
          C[(size_t)n * 1536 + col * 6 + (pos >> 1)] = bf16rn(v);
        }
      } else {
        float* C = (float*)Cout;
#pragma unroll
        for (int j = 0; j < 4; ++j) {
          int m = mbase + j;
          int b = m >> 9, tt = m & 511;
          C[((size_t)tt * 16 + b) * 1536 + col] = acc[mi][ni][j] + bv;
        }
      }
    }
  }
}

// ---------------- persistent GRU: 2 independent groups x 8 WGs (batch-split) ----------------
// Group g = blockIdx>>3 handles batch [8g, 8g+8); member w' = blockIdx&7 owns
// h-dims [w'*64, w'*64+64) for all 3 gates (192 rows = 12 tiles of 16; 6 waves
// x 2 tiles).  MFMA M=8 (A rows 8..15 unused).  Exchange: r11-proven tagged
// 8B protocol among the 8 group members only; groups fully independent ->
// straggler term is max-over-8, not global max-over-16.
__global__ __launch_bounds__(384) void gru_persistent(
    const float* __restrict__ h0, const float* __restrict__ gi,
    const float* __restrict__ whh, const float* __restrict__ bhh,
    float* __restrict__ hsbuf, unsigned long long* __restrict__ hxt) {
  __shared__ float gh_lds[12 * 256];     // [tile][batchslot16][dim16]
  __shared__ unsigned afl[16 * 64 * 4];  // 16KB A-fragments (rows>=8 unused)
  const int tid = threadIdx.x;
  const int g = blockIdx.x >> 3, wp = blockIdx.x & 7;
  const int l = tid & 63, v = tid >> 6;  // wave 0..5
  const int fr = l & 15, fq = l >> 4;
  unsigned long long* hxg = hxt + (size_t)g * 4096;  // group base (8B units)

  // persistent Whh B-fragments: 2 tiles/wave x 16 K-frags (128 VGPR)
  const int t0 = 2 * v, t1 = 2 * v + 1;
  const int o0 = (t0 >> 2) * 512 + wp * 64 + (t0 & 3) * 16 + fr;
  const int o1 = (t1 >> 2) * 512 + wp * 64 + (t1 & 3) * 16 + fr;
  short8 bf0[16], bf1[16];
#pragma unroll
  for (int s = 0; s < 16; ++s) {
    const float* wp0 = whh + (size_t)o0 * 512 + s * 32 + fq * 8;
    const float* wp1 = whh + (size_t)o1 * 512 + s * 32 + fq * 8;
    float4 a0 = *(const float4*)wp0, a1 = *(const float4*)(wp0 + 4);
    float4 c0 = *(const float4*)wp1, c1 = *(const float4*)(wp1 + 4);
    short8 x, y;
    x[0] = (short)bf16rn(a0.x); x[1] = (short)bf16rn(a0.y);
    x[2] = (short)bf16rn(a0.z); x[3] = (short)bf16rn(a0.w);
    x[4] = (short)bf16rn(a1.x); x[5] = (short)bf16rn(a1.y);
    x[6] = (short)bf16rn(a1.z); x[7] = (short)bf16rn(a1.w);
    y[0] = (short)bf16rn(c0.x); y[1] = (short)bf16rn(c0.y);
    y[2] = (short)bf16rn(c0.z); y[3] = (short)bf16rn(c0.w);
    y[4] = (short)bf16rn(c1.x); y[5] = (short)bf16rn(c1.y);
    y[6] = (short)bf16rn(c1.z); y[7] = (short)bf16rn(c1.w);
    bf0[s] = x; bf1[s] = y;
  }
  const float bo0 = bhh[o0], bo1 = bhh[o1];

  // gate threads (tid<256): (b8 = tid>>5, jp = tid&31) -> pair (jl, jl+1)
  const int b8 = tid >> 5, jp = tid & 31, jl = jp * 2;
  const bool gthr = (tid < 256);
  const int pt = tid - 256;              // poller 0..127 (waves 4,5)
  const int bglob = g * 8 + b8;
  const int jglob = wp * 64 + jl;
  float hA = 0.f, hB = 0.f;
  float giC0 = 0.f, giC1 = 0.f, giC2 = 0.f, giC3 = 0.f, giC4 = 0.f, giC5 = 0.f;
  float giN0 = 0.f, giN1 = 0.f, giN2 = 0.f, giN3 = 0.f, giN4 = 0.f, giN5 = 0.f;
  if (gthr) {
    float2 h2 = *(const float2*)(h0 + (size_t)bglob * 512 + jglob);
    hA = h2.x; hB = h2.y;
    const float* g0 = gi + (size_t)bglob * 1536 + jglob;             // gi[0]
    float2 r0 = *(const float2*)(g0);
    float2 r1 = *(const float2*)(g0 + 512);
    float2 r2 = *(const float2*)(g0 + 1024);
    giC0 = r0.x; giC3 = r0.y; giC1 = r1.x; giC4 = r1.y; giC2 = r2.x; giC5 = r2.y;
    const float* g1 = gi + (size_t)(16 + bglob) * 1536 + jglob;      // gi[1]
    float2 s0 = *(const float2*)(g1);
    float2 s1 = *(const float2*)(g1 + 512);
    float2 s2 = *(const float2*)(g1 + 1024);
    giN0 = s0.x; giN3 = s0.y; giN1 = s1.x; giN4 = s1.y; giN2 = s2.x; giN5 = s2.y;
  }

  // ---- prologue: pollers fetch h_0 (parity 0, tag 0, all 16 frags) ----
  if (!gthr) {
    const int ps = pt >> 3;              // frag 0..15
    const int pw0 = (pt & 7) * 2;        // word base within frag
    const unsigned long long* base = hxg + ps * 128;
    uint4v r[8];
    for (;;) {
#pragma unroll
      for (int q = 0; q < 8; ++q)
        asm volatile("global_load_dwordx4 %0, %1, off sc0 sc1"
                     : "=v"(r[q]) : "v"(base + pw0 + q * 16));
      asm volatile("s_waitcnt vmcnt(0)" ::: "memory");
      __builtin_amdgcn_sched_barrier(0);
      bool ok = true;
#pragma unroll
      for (int q = 0; q < 8; ++q)
        ok = ok & (r[q].y == 0u) & (r[q].w == 0u);
      if (ok) break;
    }
#pragma unroll
    for (int q = 0; q < 8; ++q) {
      int w_i = pw0 + q * 16;
      int lane = ((w_i >> 2) & 7) + 16 * (w_i >> 5);
      *(uint2*)&afl[(ps * 64 + lane) * 4 + (w_i & 3)] = make_uint2(r[q].x, r[q].z);
    }
  }
  wg_barrier();

  for (int t = 0; t < T_; ++t) {
    // ---- phase 1: MFMA gh = h_t @ Whh^T (2 tiles/wave, 4 chains) ----
    f32x4 e0 = (f32x4)0.f, q0 = (f32x4)0.f, e1 = (f32x4)0.f, q1 = (f32x4)0.f;
#pragma unroll
    for (int s = 0; s < 16; s += 2) {
      union { uint4v u; short8 s8; } ca, cb;
      ca.u = *(const uint4v*)&afl[((s + 0) * 64 + l) * 4];
      cb.u = *(const uint4v*)&afl[((s + 1) * 64 + l) * 4];
      e0 = __builtin_amdgcn_mfma_f32_16x16x32_bf16(ca.s8, bf0[s], e0, 0, 0, 0);
      q0 = __builtin_amdgcn_mfma_f32_16x16x32_bf16(cb.s8, bf0[s + 1], q0, 0, 0, 0);
      e1 = __builtin_amdgcn_mfma_f32_16x16x32_bf16(ca.s8, bf1[s], e1, 0, 0, 0);
      q1 = __builtin_amdgcn_mfma_f32_16x16x32_bf16(cb.s8, bf1[s + 1], q1, 0, 0, 0);
    }
#pragma unroll
    for (int j = 0; j < 4; ++j) {
      gh_lds[t0 * 256 + (fq * 4 + j) * 16 + fr] = e0[j] + q0[j] + bo0;
      gh_lds[t1 * 256 + (fq * 4 + j) * 16 + fr] = e1[j] + q1[j] + bo1;
    }
    wg_barrier();

    // ---- phase 2: gates+store (waves 0-3) || poll t+1 (waves 4-5) ----
    if (gthr) {
      const int hh = jl >> 4, c = jl & 15;
      float2 rr = *(const float2*)&gh_lds[(0 + hh) * 256 + b8 * 16 + c];
      float2 zz = *(const float2*)&gh_lds[(4 + hh) * 256 + b8 * 16 + c];
      float2 nn = *(const float2*)&gh_lds[(8 + hh) * 256 + b8 * 16 + c];
      float rgA = __builtin_amdgcn_rcpf(1.f + __expf(-(giC0 + rr.x)));
      float rgB = __builtin_amdgcn_rcpf(1.f + __expf(-(giC3 + rr.y)));
      float zgA = __builtin_amdgcn_rcpf(1.f + __expf(-(giC1 + zz.x)));
      float zgB = __builtin_amdgcn_rcpf(1.f + __expf(-(giC4 + zz.y)));
      float eA = __expf(2.f * (giC2 + rgA * nn.x));
      float eB = __expf(2.f * (giC5 + rgB * nn.y));
      float ngA = 1.f - 2.f * __builtin_amdgcn_rcpf(eA + 1.f);
      float ngB = 1.f - 2.f * __builtin_amdgcn_rcpf(eB + 1.f);
      hA = (1.f - zgA) * ngA + zgA * hA;
      hB = (1.f - zgB) * ngB + zgB * hB;
      // tagged 8B agent store = data + release flag in one transaction
      if (t + 1 < T_) {
        unsigned pk = (unsigned)bf16rn(hA) | ((unsigned)bf16rn(hB) << 16);
        unsigned long long payload =
            (unsigned long long)pk | ((unsigned long long)(unsigned)(t + 1) << 32);
        int s = wp * 2 + (jl >> 5);
        int w_i = (((jl & 31) >> 3) * 8 + b8) * 4 + (jp & 3);
        __hip_atomic_store(hxg + ((t + 1) & 1) * 2048 + s * 128 + w_i, payload,
                           __ATOMIC_RELAXED, __HIP_MEMORY_SCOPE_AGENT);
      }
      // off-critical-path: fp32 h for fc3; shift gi pipeline; prefetch gi[t+2]
      *(float2*)(hsbuf + ((size_t)t * 16 + bglob) * 512 + jglob) =
          make_float2(hA, hB);
      giC0 = giN0; giC1 = giN1; giC2 = giN2;
      giC3 = giN3; giC4 = giN4; giC5 = giN5;
      if (t + 2 < T_) {
        const float* gb = gi + ((size_t)(t + 2) * 16 + bglob) * 1536 + jglob;
        float2 r0 = *(const float2*)(gb);
        float2 r1 = *(const float2*)(gb + 512);
        float2 r2 = *(const float2*)(gb + 1024);
        giN0 = r0.x; giN3 = r0.y; giN1 = r1.x; giN4 = r1.y; giN2 = r2.x; giN5 = r2.y;
      }
    } else if (t + 1 < T_) {
      const int ps = pt >> 3;
      const int pw0 = (pt & 7) * 2;
      const unsigned long long* base =
          hxg + ((t + 1) & 1) * 2048 + ps * 128;
      const unsigned tag = (unsigned)(t + 1);
      uint4v r[8];
      for (;;) {
#pragma unroll
        for (int q = 0; q < 8; ++q)
          asm volatile("global_load_dwordx4 %0, %1, off sc0 sc1"
                       : "=v"(r[q]) : "v"(base + pw0 + q * 16));
        asm volatile("s_waitcnt vmcnt(0)" ::: "memory");
        __builtin_amdgcn_sched_barrier(0);
        bool ok = true;
#pragma unroll
        for (int q = 0; q < 8; ++q)
          ok = ok & (r[q].y == tag) & (r[q].w == tag);
        if (ok) break;
      }
#pragma unroll
      for (int q = 0; q < 8; ++q) {
        int w_i = pw0 + q * 16;
        int lane = ((w_i >> 2) & 7) + 16 * (w_i >> 5);
        *(uint2*)&afl[(ps * 64 + lane) * 4 + (w_i & 3)] = make_uint2(r[q].x, r[q].z);
      }
    }
    wg_barrier();
  }
}

// ---------------- fc3 ----------------
__global__ __launch_bounds__(256) void fc3_kernel(
    const float* __restrict__ hs, const float* __restrict__ w3,
    const float* __restrict__ b3, float* __restrict__ out) {
  __shared__ float w[512];
  const int tid = threadIdx.x;
  w[tid] = w3[tid];
  w[tid + 256] = w3[tid + 256];
  __syncthreads();
  const int gidx = blockIdx.x * 256 + tid;  // b*512 + t
  const int b = gidx >> 9, t = gidx & 511;
  const float4* hr = (const float4*)(hs + ((size_t)t * 16 + b) * 512);
  const float4* wr = (const float4*)w;
  float acc = 0.f;
#pragma unroll 8
  for (int kc = 0; kc < 128; ++kc) {
    float4 h = hr[kc], ww = wr[kc];
    acc += h.x * ww.x + h.y * ww.y + h.z * ww.z + h.w * ww.w;
  }
  out[gidx] = acc + b3[0];
}

// ---------------------------------------------------------------------------
extern "C" void kernel_launch(void* const* d_in, const int* in_sizes, int n_in,
                              void* d_out, int out_size, void* d_ws,
                              size_t ws_size, hipStream_t stream) {
  const float* phone = (const float*)d_in[0];
  const float* h0    = (const float*)d_in[1];
  const float* w1    = (const float*)d_in[2];
  const float* b1    = (const float*)d_in[3];
  const float* w2    = (const float*)d_in[4];
  const float* b2    = (const float*)d_in[5];
  const float* fc1w  = (const float*)d_in[6];
  const float* fc1b  = (const float*)d_in[7];
  const float* fc2w  = (const float*)d_in[8];
  const float* fc2b  = (const float*)d_in[9];
  const float* wih   = (const float*)d_in[10];
  const float* whh   = (const float*)d_in[11];
  const float* bih   = (const float*)d_in[12];
  const float* bhh   = (const float*)d_in[13];
  const float* w3    = (const float*)d_in[14];
  const float* b3    = (const float*)d_in[15];
  float* out = (float*)d_out;

  char* ws = (char*)d_ws;
  ushort* out1b = (ushort*)(ws + 0);            // 41,943,040
  ushort* feat2 = (ushort*)(ws + 41943040);     // 25,165,824
  ushort* feat3 = (ushort*)(ws + 67108864);     // 16,777,216 (dead after fc2)
  ushort* feat4 = (ushort*)(ws + 83886080);     //  8,388,608
  float*  gibuf = (float*) (ws + 92274688);     // 50,331,648  [t][b][1536]
  float*  hsbuf = (float*) (ws + 142606336);    // 16,777,216  [t][b][512]
  ushort* w2b   = (ushort*)(ws + 159383552);    //    589,824
  ushort* fc1wb = (ushort*)(ws + 159973376);    //  3,145,728
  ushort* fc2wb = (ushort*)(ws + 163119104);    //  1,048,576
  ushort* wihb  = (ushort*)(ws + 164167680);    //  1,572,864
  // tagged h-exchange: 2 groups x 2 parities x 16KB = 64KB (dead feat3 region)
  unsigned long long* hxt = (unsigned long long*)(ws + 67108864);

  f32_to_bf16<<<288, 256, 0, stream>>>(w2, w2b, 73728);
  f32_to_bf16<<<1536, 256, 0, stream>>>(fc1w, fc1wb, 393216);
  f32_to_bf16<<<512, 256, 0, stream>>>(fc2w, fc2wb, 131072);
  f32_to_bf16<<<768, 256, 0, stream>>>(wih, wihb, 196608);

  conv1_kernel<<<1024, 256, 0, stream>>>(phone, w1, b1, out1b);
  gemm_bf16<1, 1><<<dim3(768, 2), 256, 0, stream>>>(out1b, w2b, b2, feat2, 1152, 0, 0);
  gemm_bf16<0, 0><<<dim3(64, 8), 256, 0, stream>>>(feat2, fc1wb, fc1b, feat3, 1536, 1536, 1024);
  gemm_bf16<0, 0><<<dim3(64, 4), 256, 0, stream>>>(feat3, fc2wb, fc2b, feat4, 1024, 1024, 512);
  gemm_bf16<0, 2><<<dim3(64, 12), 256, 0, stream>>>(feat4, wihb, bih, gibuf, 512, 512, 1536);

  // clear all 4 tag buffers (replay-safe), stage h0, run recurrence
  hipMemsetAsync(hxt, 0, 65536, stream);
  stage_h0<<<1, 256, 0, stream>>>(h0, hxt);
  gru_persistent<<<16, 384, 0, stream>>>(h0, gibuf, whh, bhh, hsbuf, hxt);

  fc3_kernel<<<32, 256, 0, stream>>>(hsbuf, w3, b3, out);
}